// Round 11
// baseline (254.648 us; speedup 1.0000x reference)
//
#include <hip/hip_runtime.h>
#include <hip/hip_bf16.h>

// Fused attention block: QKV proj -> causal flash attention -> out proj.
// R10 = R9 resubmission (infra timeout, never benched).
// GEMM: single-barrier-per-K-tile persistent kernel (ds_read||MFMA overlap
// across waves), LDS 96KB (A 2x16K + B 2x32K), grid 256, 3 tiles/block for
// QKV proj. Coalesced LDS-repack epilogue. Attention: R3 swapped-QK^T.

typedef unsigned short u16;
typedef unsigned int   u32;
typedef __attribute__((ext_vector_type(8))) short bf16x8;
typedef __attribute__((ext_vector_type(4))) float f32x4;
typedef __attribute__((ext_vector_type(16))) float f32x16;
typedef __attribute__((ext_vector_type(4))) u32 u32x4;
typedef __attribute__((ext_vector_type(2))) u32 u32x2;

#define AS1 __attribute__((address_space(1)))
#define AS3 __attribute__((address_space(3)))
#define FENCE asm volatile("" ::: "memory")
#define BAR() do { FENCE; __builtin_amdgcn_s_barrier(); FENCE; } while (0)

__device__ __forceinline__ u16 f2bf(float f) {
  u32 x = __float_as_uint(f);
  x += 0x7fffu + ((x >> 16) & 1u);
  return (u16)(x >> 16);
}
__device__ __forceinline__ u32 pk2(float a, float b) {
  return (u32)f2bf(a) | ((u32)f2bf(b) << 16);
}

// ---------- fused fp32->bf16 conversion + bias build ----------
__global__ __launch_bounds__(256) void cvt_all(const float* __restrict__ hs,
                                               const float* __restrict__ Wq,
                                               const float* __restrict__ Wk,
                                               const float* __restrict__ Wv,
                                               const float* __restrict__ Wo,
                                               const float* __restrict__ bq,
                                               const float* __restrict__ bv,
                                               u16* __restrict__ Xb,
                                               u16* __restrict__ Wqkv,
                                               u16* __restrict__ Wob,
                                               float* __restrict__ bias) {
  if (blockIdx.x == gridDim.x - 1) {
    for (int i = threadIdx.x; i < 3072; i += 256) {
      float v = 0.f;
      if (i < 1024) v = bq[i];
      else if (i >= 2048) v = bv[i - 2048];
      bias[i] = v;
    }
  }
  int i = blockIdx.x * 256 + threadIdx.x;
  const int stride = gridDim.x * 256;
  for (; i < 3145728; i += stride) {
    const float* src;
    u16* dst;
    int off;
    if (i < 2097152) {
      src = hs; dst = Xb; off = i;
    } else {
      int j = i - 2097152;
      int m = j >> 18;
      off = j & 262143;
      src = (m == 0) ? Wq : (m == 1) ? Wk : (m == 2) ? Wv : Wo;
      dst = (m < 3) ? (Wqkv + (size_t)m * 1048576) : Wob;
    }
    float4 v = ((const float4*)src)[off];
    u32 lo = (u32)f2bf(v.x) | ((u32)f2bf(v.y) << 16);
    u32 hi = (u32)f2bf(v.z) | ((u32)f2bf(v.w) << 16);
    ((u32*)dst)[off * 2]     = lo;
    ((u32*)dst)[off * 2 + 1] = hi;
  }
}

// ---------------- 128x256 single-barrier persistent bf16 NT GEMM ----------
// C[m][n] = sum_k A[m][k]*B[n][k] + bias[n].  BK=64, 8 waves (2Mx4N),
// wave tile 64x64. A 2-buf (16KB) + B 2-buf (32KB) = 96KB LDS. Grid 256
// persistent blocks; NTILES tiles per block.
template <int OUT_MODE, int NTILES>
__global__ __launch_bounds__(512, 2) void gemmP(const u16* __restrict__ A,
                                                const u16* __restrict__ Bw,
                                                const float* __restrict__ bias,
                                                void* __restrict__ C,
                                                int M, int N, int K, int nbn) {
  __shared__ __align__(16) unsigned char smem[98304];
  auto bufA = [&](int p) -> u16* { return (u16*)(smem + (size_t)p * 16384); };
  auto bufB = [&](int p) -> u16* { return (u16*)(smem + 32768 + (size_t)p * 32768); };

  const int swz = ((int)blockIdx.x & 7) * 32 + ((int)blockIdx.x >> 3);  // XCD
  const int tid = threadIdx.x;
  const int l = tid & 63, w = tid >> 6;
  const int l15 = l & 15, lg = (l >> 4) & 3;
  const int wr = w >> 2, wc = w & 3;   // wave grid 2(M) x 4(N)

  // staging coords: unit = 128 rows x 64 cols; slot row = j*64 + w*8 + (l>>3)
  const int sr = w * 8 + (l >> 3);
  const int sch = (l & 7) ^ ((l >> 3) & 7);   // pre-swizzled source chunk
  const int sldso = w * 64 * 8;               // u16 offset of wave dest (j=0)

  auto STG = [&](const u16* src, u16* lds) {   // one 128x64 unit (2 loads/thr)
#pragma unroll
    for (int j = 0; j < 2; ++j)
      __builtin_amdgcn_global_load_lds(
          (const AS1 void*)(src + (size_t)(j * 64 + sr) * K + sch * 8),
          (AS3 void*)((AS3 u16*)lds + j * 4096 + sldso), 16, 0, 0);
  };
  auto LDA = [&](const u16* Ah, int m, int kk) -> bf16x8 {
    int row = wr * 64 + m * 16 + l15;
    int ch = (kk * 4 + lg) ^ (l15 & 7);
    return *(const bf16x8*)&Ah[row * 64 + ch * 8];
  };
  auto LDB = [&](const u16* Bh, int n, int kk) -> bf16x8 {
    int row = wc * 64 + n * 16 + l15;
    int ch = (kk * 4 + lg) ^ (l15 & 7);
    return *(const bf16x8*)&Bh[row * 64 + ch * 8];
  };

  const int NT = K >> 6;

#pragma unroll 1
  for (int ti = 0; ti < NTILES; ++ti) {
    const int t = swz + ti * 256;
    const int bn = t % nbn, bm = t / nbn;
    const u16* Ab = A + (size_t)(bm * 128) * K;
    const u16* Bb = Bw + (size_t)(bn * 256) * K;

    // ---- prologue: stage kt0 -> buf0, kt1 -> buf1 (12 loads) ----
    STG(Ab, bufA(0));
    STG(Bb, bufB(0));
    STG(Bb + (size_t)128 * K, bufB(0) + 8192);
    STG(Ab + 64, bufA(1));
    STG(Bb + 64, bufB(1));
    STG(Bb + (size_t)128 * K + 64, bufB(1) + 8192);
    asm volatile("s_waitcnt vmcnt(0)" ::: "memory");
    BAR();

    f32x4 acc[4][4] = {};  // [m][n], wave tile 64x64

#pragma unroll 1
    for (int kt = 0; kt < NT; ++kt) {
      const int p = kt & 1;
      const u16* Ah = bufA(p);
      const u16* Bh = bufB(p);
      bf16x8 af[4][2], bf[4][2];
      // ---- read ALL fragments for this K-tile (16 x ds_read_b128) ----
#pragma unroll
      for (int m = 0; m < 4; ++m)
#pragma unroll
        for (int kk = 0; kk < 2; ++kk) af[m][kk] = LDA(Ah, m, kk);
#pragma unroll
      for (int n = 0; n < 4; ++n)
#pragma unroll
        for (int kk = 0; kk < 2; ++kk) bf[n][kk] = LDB(Bh, n, kk);
      asm volatile("s_waitcnt lgkmcnt(0)" ::: "memory");
      __builtin_amdgcn_sched_barrier(0);
      // kt+1's staging (issued last iter) must have landed on ALL waves
      asm volatile("s_waitcnt vmcnt(0)" ::: "memory");
      BAR();
      // ---- stage kt+2 into the buffer we just finished reading ----
      if (kt + 2 < NT) {
        STG(Ab + (kt + 2) * 64, bufA(p));
        STG(Bb + (kt + 2) * 64, bufB(p));
        STG(Bb + (size_t)128 * K + (kt + 2) * 64, bufB(p) + 8192);
      }
      // ---- 32 MFMA (register-only; overlaps other waves' next ds_reads) ----
      __builtin_amdgcn_s_setprio(1);
#pragma unroll
      for (int m = 0; m < 4; ++m)
#pragma unroll
        for (int n = 0; n < 4; ++n)
#pragma unroll
          for (int kk = 0; kk < 2; ++kk)
            acc[m][n] = __builtin_amdgcn_mfma_f32_16x16x32_bf16(
                af[m][kk], bf[n][kk], acc[m][n], 0, 0, 0);
      __builtin_amdgcn_s_setprio(0);
    }

    // ---- epilogue: repack through LDS -> coalesced stores, fused bias ----
    float* eb = (float*)smem;  // [128][132] f32, 67.6KB (bufs dead here)
    const int mychunk = wc >> 1;
#pragma unroll
    for (int ch = 0; ch < 2; ++ch) {
      __syncthreads();
      if (mychunk == ch) {
#pragma unroll
        for (int m = 0; m < 4; ++m)
#pragma unroll
          for (int n = 0; n < 4; ++n)
#pragma unroll
            for (int i = 0; i < 4; ++i)
              eb[(wr * 64 + m * 16 + lg * 4 + i) * 132 + (wc & 1) * 64 + n * 16 + l15] =
                  acc[m][n][i];
      }
      __syncthreads();
#pragma unroll
      for (int ps = 0; ps < 8; ++ps) {
        int idx = (ps * 512 + tid) * 4;
        int row = idx >> 7, col = idx & 127;
        f32x4 v = *(const f32x4*)&eb[row * 132 + col];
        int colg = bn * 256 + ch * 128 + col;
        f32x4 b = *(const f32x4*)&bias[colg];
        size_t go = (size_t)(bm * 128 + row) * N + colg;
        if (OUT_MODE == 0) {
          u32x2 o;
          o[0] = pk2(v[0] + b[0], v[1] + b[1]);
          o[1] = pk2(v[2] + b[2], v[3] + b[3]);
          *(u32x2*)((u16*)C + go) = o;
        } else {
          f32x4 o = {v[0] + b[0], v[1] + b[1], v[2] + b[2], v[3] + b[3]};
          *(f32x4*)((float*)C + go) = o;
        }
      }
    }
    __syncthreads();  // eb reads done before next tile's prologue staging
  }
}

// ---------------- flash attention: swapped-QK^T 32x32 structure -----------
__global__ __launch_bounds__(256, 4) void attn_kernel(const u16* __restrict__ qkv,
                                                      u16* __restrict__ attnout) {
  const int bid = (blockIdx.x & 7) * 128 + (blockIdx.x >> 3);  // XCD: 1 seq/XCD
  const int qb = 7 - (bid & 7);                                // longest first
  const int h = (bid >> 3) & 15;
  const int s = bid >> 7;
  const int tid = threadIdx.x;
  const int l = tid & 63, w = tid >> 6;
  const int l31 = l & 31;
  const int hi = l >> 5;
  const int pb = (l >> 3) & 1;

  __shared__ __align__(16) u16 Ks[128 * 64];   // XOR-swizzled [kv][d]
  __shared__ __align__(16) u32 Vt2[64 * 65];   // [d][kvpair], pad 65

  const u16* kbase = qkv + (size_t)(s * 1024) * 3072 + 1024 + h * 64;
  const u16* vbase = qkv + (size_t)(s * 1024) * 3072 + 2048 + h * 64;

  bf16x8 qf[4];
  {
    const u16* qptr = qkv + (size_t)(s * 1024 + qb * 128 + w * 32 + l31) * 3072 + h * 64 + hi * 8;
#pragma unroll
    for (int c = 0; c < 4; ++c) qf[c] = *(const bf16x8*)(qptr + c * 16);
  }

  float m_r = -1e30f, l_r = 0.f;
  f32x16 o0 = {}, o1 = {};

  const int nt = qb + 1;

  const int vkv = w * 8 + (l >> 3);
  const int vd0 = (l & 7) * 8;
  const int vkp = w * 4 + (l >> 4);
  const int dEff = vd0 + pb * 4;

  const int srow = w * 8 + (l >> 3);
  const int schunk = (l & 7) ^ ((l >> 3) & 7);

  bf16x8 vcur[4], vnx[4];
#pragma unroll
  for (int p = 0; p < 4; ++p)
    vcur[p] = *(const bf16x8*)(vbase + (size_t)(p * 32 + vkv) * 3072 + vd0);

  for (int t = 0; t < nt; ++t) {
    const u16* kt = kbase + (size_t)(t * 128) * 3072;
#pragma unroll
    for (int p = 0; p < 4; ++p)
      __builtin_amdgcn_global_load_lds(
          (const AS1 void*)(kt + (size_t)(p * 32 + srow) * 3072 + schunk * 8),
          (AS3 void*)((AS3 u16*)Ks + p * 2048 + w * 512), 16, 0, 0);

#pragma unroll
    for (int p = 0; p < 4; ++p) {
      u32 dw0 = ((u32*)&vcur[p])[0], dw1 = ((u32*)&vcur[p])[1];
      u32 dw2 = ((u32*)&vcur[p])[2], dw3 = ((u32*)&vcur[p])[3];
      u32 s0 = (u32)__shfl_xor((int)(pb ? dw0 : dw2), 8, 64);
      u32 s1 = (u32)__shfl_xor((int)(pb ? dw1 : dw3), 8, 64);
      u32 md0 = pb ? dw2 : dw0, md1 = pb ? dw3 : dw1;
      u32 lo0 = pb ? s0 : md0, hi0 = pb ? md0 : s0;
      u32 lo1 = pb ? s1 : md1, hi1 = pb ? md1 : s1;
      int kp = p * 16 + vkp;
      Vt2[(dEff + 0) * 65 + kp] = (lo0 & 0xffffu) | (hi0 << 16);
      Vt2[(dEff + 1) * 65 + kp] = (lo0 >> 16) | (hi0 & 0xffff0000u);
      Vt2[(dEff + 2) * 65 + kp] = (lo1 & 0xffffu) | (hi1 << 16);
      Vt2[(dEff + 3) * 65 + kp] = (lo1 >> 16) | (hi1 & 0xffff0000u);
    }
    __syncthreads();

    if (t + 1 < nt) {
      const u16* vt = vbase + (size_t)((t + 1) * 128) * 3072;
#pragma unroll
      for (int p = 0; p < 4; ++p)
        vnx[p] = *(const bf16x8*)(vt + (size_t)(p * 32 + vkv) * 3072 + vd0);
    }

    const bool diag = (t == nt - 1);
#pragma unroll
    for (int sub = 0; sub < 4; ++sub) {
      if (!(diag && sub > w)) {
        f32x16 sc = {};
#pragma unroll
        for (int c = 0; c < 4; ++c) {
          int r = sub * 32 + l31;
          int pc = (2 * c + hi) ^ (l31 & 7);
          bf16x8 kf = *(const bf16x8*)&Ks[r * 64 + pc * 8];
          sc = __builtin_amdgcn_mfma_f32_32x32x16_bf16(kf, qf[c], sc, 0, 0, 0);
        }
        float tv[16];
#pragma unroll
        for (int r = 0; r < 16; ++r) tv[r] = sc[r] * 0.125f;
        if (diag && sub == w) {
#pragma unroll
          for (int r = 0; r < 16; ++r) {
            int kvloc = (r & 3) + 8 * (r >> 2) + 4 * hi;
            if (kvloc > l31) tv[r] = -1e30f;
          }
        }
        float t0 = fmaxf(fmaxf(tv[0], tv[1]), fmaxf(tv[2], tv[3]));
        float t1 = fmaxf(fmaxf(tv[4], tv[5]), fmaxf(tv[6], tv[7]));
        float t2 = fmaxf(fmaxf(tv[8], tv[9]), fmaxf(tv[10], tv[11]));
        float t3 = fmaxf(fmaxf(tv[12], tv[13]), fmaxf(tv[14], tv[15]));
        float tmax = fmaxf(fmaxf(t0, t1), fmaxf(t2, t3));
        tmax = fmaxf(tmax, __shfl_xor(tmax, 32, 64));
        if (!__all(tmax <= m_r + 8.0f)) {
          float nm = fmaxf(m_r, tmax);
          float alpha = __expf(m_r - nm);
          m_r = nm;
          l_r *= alpha;
#pragma unroll
          for (int r = 0; r < 16; ++r) { o0[r] *= alpha; o1[r] *= alpha; }
        }
#pragma unroll
        for (int r = 0; r < 16; ++r) tv[r] = __expf(tv[r] - m_r);
        float s0_ = (tv[0] + tv[1]) + (tv[2] + tv[3]);
        float s1_ = (tv[4] + tv[5]) + (tv[6] + tv[7]);
        float s2_ = (tv[8] + tv[9]) + (tv[10] + tv[11]);
        float s3_ = (tv[12] + tv[13]) + (tv[14] + tv[15]);
        float psum = (s0_ + s1_) + (s2_ + s3_);
        psum += __shfl_xor(psum, 32, 64);
        l_r += psum;
#pragma unroll
        for (int s01 = 0; s01 < 2; ++s01) {
          u32 W0 = pk2(tv[8 * s01 + 0], tv[8 * s01 + 1]);
          u32 W1 = pk2(tv[8 * s01 + 2], tv[8 * s01 + 3]);
          u32 X0 = pk2(tv[8 * s01 + 4], tv[8 * s01 + 5]);
          u32 X1 = pk2(tv[8 * s01 + 6], tv[8 * s01 + 7]);
          u32 rW0 = (u32)__shfl_xor((int)W0, 32, 64);
          u32 rW1 = (u32)__shfl_xor((int)W1, 32, 64);
          u32 rX0 = (u32)__shfl_xor((int)X0, 32, 64);
          u32 rX1 = (u32)__shfl_xor((int)X1, 32, 64);
          u32x4 av;
          av[0] = hi ? rX0 : W0;
          av[1] = hi ? rX1 : W1;
          av[2] = hi ? X0 : rW0;
          av[3] = hi ? X1 : rW1;
          bf16x8 pa = *(bf16x8*)&av;
          int kpb = sub * 16 + s01 * 8 + hi * 4;
          u32x4 v0 = *(const u32x4*)&Vt2[(size_t)l31 * 65 + kpb];
          o0 = __builtin_amdgcn_mfma_f32_32x32x16_bf16(pa, *(bf16x8*)&v0, o0, 0, 0, 0);
          u32x4 v1 = *(const u32x4*)&Vt2[(size_t)(32 + l31) * 65 + kpb];
          o1 = __builtin_amdgcn_mfma_f32_32x32x16_bf16(pa, *(bf16x8*)&v1, o1, 0, 0, 0);
        }
      }
    }
    __syncthreads();
#pragma unroll
    for (int p = 0; p < 4; ++p) vcur[p] = vnx[p];
  }

#pragma unroll
  for (int r = 0; r < 16; ++r) {
    int qp = (r & 3) + 8 * (r >> 2) + 4 * hi;
    float ls = __shfl(l_r, qp, 64);
    float inv = __builtin_amdgcn_rcpf(ls);
    int trow = s * 1024 + qb * 128 + w * 32 + qp;
    attnout[(size_t)trow * 1024 + h * 64 + l31]      = f2bf(o0[r] * inv);
    attnout[(size_t)trow * 1024 + h * 64 + 32 + l31] = f2bf(o1[r] * inv);
  }
}

// ---------------- host launch ----------------
extern "C" void kernel_launch(void* const* d_in, const int* in_sizes, int n_in,
                              void* d_out, int out_size, void* d_ws, size_t ws_size,
                              hipStream_t stream) {
  const float* hs = (const float*)d_in[0];
  const float* Wq = (const float*)d_in[2];
  const float* bq = (const float*)d_in[3];
  const float* Wk = (const float*)d_in[4];
  const float* Wv = (const float*)d_in[5];
  const float* bv = (const float*)d_in[6];
  const float* Wo = (const float*)d_in[7];
  const float* bo = (const float*)d_in[8];

  char* ws = (char*)d_ws;
  u16* Xb    = (u16*)ws;
  u16* Wqkv  = (u16*)(ws + 16777216);
  u16* Wob   = (u16*)(ws + 23068672);
  float* bqk = (float*)(ws + 25165824);
  u16* qkv   = (u16*)(ws + 25178112);
  u16* attn  = (u16*)(ws + 75509760);

  cvt_all<<<2048, 256, 0, stream>>>(hs, Wq, Wk, Wv, Wo, bq, bv, Xb, Wqkv, Wob, bqk);

  gemmP<0, 3><<<256, 512, 0, stream>>>(Xb, Wqkv, bqk, qkv, 8192, 3072, 1024, 12);

  attn_kernel<<<1024, 256, 0, stream>>>(qkv, attn);

  gemmP<1, 1><<<256, 512, 0, stream>>>(attn, Wob, bo, d_out, 8192, 1024, 1024, 4);
}